// Round 6
// baseline (205.480 us; speedup 1.0000x reference)
//
#include <hip/hip_runtime.h>

typedef __attribute__((ext_vector_type(8))) short bf16x8;
typedef __attribute__((ext_vector_type(4))) float f32x4;

constexpr int BT   = 256;    // threads/block (4 waves)
constexpr int TP   = 64;     // pairs per tile (16 per wave)
constexpr int KD   = 96;     // feature/hidden dim
constexpr int LDX  = 104;    // xs row stride in bf16 (208 B: 16B-aligned)
constexpr int NBLK = 1024;   // persistent blocks (4 per CU)

// d_ws layout: [wfrag: 36 frags * 64 lanes * 8 bf16 = 36864 B][gbf: 48000 bf16 = 96000 B]
constexpr int WFRAG_USHORTS = 36 * 64 * 8;

__device__ inline ushort f2bf(float f) {  // fp32 -> bf16 RNE
    uint u = __float_as_uint(f);
    u += 0x7fffu + ((u >> 16) & 1u);
    return (ushort)(u >> 16);
}

// prep A: geoms f32 -> bf16 table
__global__ void prep_geoms(const float* __restrict__ g, ushort* __restrict__ gb, int n) {
    int i = blockIdx.x * 256 + threadIdx.x;
    if (i < n) gb[i] = f2bf(g[i]);
}

// prep B: pack W1/W2 into fragment-major bf16 table.
// Element j of frag (L,mt,kb) for lane (g=lane>>4, cl=lane&15) is
// W[(kb*32+g*8+j)*96 + mt*16+cl]  (matches the LDS w?t read of rounds 2-5).
__global__ void prep_wfrag(const float* __restrict__ W1, const float* __restrict__ W2,
                           ushort* __restrict__ wf) {
    int id = blockIdx.x * 256 + threadIdx.x;       // 0 .. 2303
    if (id >= 36 * 64) return;
    int lane = id & 63;
    int f    = id >> 6;          // 0..35
    int L    = f / 18;
    int fr   = f - L * 18;
    int mt   = fr / 3;
    int kb   = fr - mt * 3;
    int g    = lane >> 4;
    int cl   = lane & 15;
    const float* W = L ? W2 : W1;
    ushort* dst = wf + (size_t)id * 8;
    #pragma unroll
    for (int j = 0; j < 8; ++j)
        dst[j] = f2bf(W[(kb * 32 + g * 8 + j) * KD + mt * 16 + cl]);
}

__global__ void __launch_bounds__(BT, 4) collision_mfma(
    const int* __restrict__ o1, const int* __restrict__ o2,
    const float* __restrict__ Tg, const float* __restrict__ geoms,
    const ushort* __restrict__ gbf, const ushort* __restrict__ wfrag,
    const float* __restrict__ b1, const float* __restrict__ b2,
    const float* __restrict__ W3, const float* __restrict__ b3,
    float* __restrict__ out, int N)
{
    __shared__ ushort xs[128 * LDX];    // x/h tile bf16, wave-private 32-row bands (26624 B)
    __shared__ float  tinv[64 * 16];    // per-pair inverse rows 0..2, stride 16 floats (4096 B)

    const int tid = threadIdx.x;
    const int w   = tid >> 6;      // wave 0..3
    const int l   = tid & 63;      // lane
    const int cl  = l & 15;        // fragment col within 16-tile
    const int g   = l >> 4;        // k-group 0..3
    const int rg  = g * 4;

    const int ntiles = N / TP;

    for (int tile = blockIdx.x; tile < ntiles; tile += NBLK) {
        const int pbase = tile * TP + w * 16;

        // ===== phase 1: f64 4x4 inverse, lanes 0..15, one pair each =====
        if (l < 16) {
            const int p = pbase + l;
            const float4* T4 = reinterpret_cast<const float4*>(Tg + (size_t)p * 16);
            float4 t0 = T4[0], t1 = T4[1], t2 = T4[2], t3 = T4[3];
            double m00=t0.x, m01=t0.y, m02=t0.z, m03=t0.w;
            double m10=t1.x, m11=t1.y, m12=t1.z, m13=t1.w;
            double m20=t2.x, m21=t2.y, m22=t2.z, m23=t2.w;
            double m30=t3.x, m31=t3.y, m32=t3.z, m33=t3.w;
            double A2323 = m22*m33 - m23*m32;
            double A1323 = m21*m33 - m23*m31;
            double A1223 = m21*m32 - m22*m31;
            double A0323 = m20*m33 - m23*m30;
            double A0223 = m20*m32 - m22*m30;
            double A0123 = m20*m31 - m21*m30;
            double A2313 = m12*m33 - m13*m32;
            double A1313 = m11*m33 - m13*m31;
            double A1213 = m11*m32 - m12*m31;
            double A2312 = m12*m23 - m13*m22;
            double A1312 = m11*m23 - m13*m21;
            double A1212 = m11*m22 - m12*m21;
            double A0313 = m10*m33 - m13*m30;
            double A0213 = m10*m32 - m12*m30;
            double A0312 = m10*m23 - m13*m20;
            double A0212 = m10*m22 - m12*m20;
            double A0113 = m10*m31 - m11*m30;
            double A0112 = m10*m21 - m11*m20;
            double det = m00*(m11*A2323 - m12*A1323 + m13*A1223)
                       - m01*(m10*A2323 - m12*A0323 + m13*A0223)
                       + m02*(m10*A1323 - m11*A0323 + m13*A0123)
                       - m03*(m10*A1223 - m11*A0223 + m12*A0123);
            double idet = 1.0 / det;
            float* ti = &tinv[(w * 16 + l) * 16];
            ti[0]  = (float)( idet *  (m11*A2323 - m12*A1323 + m13*A1223) );
            ti[1]  = (float)( idet * -(m01*A2323 - m02*A1323 + m03*A1223) );
            ti[2]  = (float)( idet *  (m01*A2313 - m02*A1313 + m03*A1213) );
            ti[3]  = (float)( idet * -(m01*A2312 - m02*A1312 + m03*A1212) );
            ti[4]  = (float)( idet * -(m10*A2323 - m12*A0323 + m13*A0223) );
            ti[5]  = (float)( idet *  (m00*A2323 - m02*A0323 + m03*A0223) );
            ti[6]  = (float)( idet * -(m00*A2313 - m02*A0313 + m03*A0213) );
            ti[7]  = (float)( idet *  (m00*A2312 - m02*A0312 + m03*A0212) );
            ti[8]  = (float)( idet *  (m10*A1323 - m11*A0323 + m13*A0123) );
            ti[9]  = (float)( idet * -(m00*A1323 - m01*A0323 + m03*A0123) );
            ti[10] = (float)( idet *  (m00*A1313 - m01*A0313 + m03*A0113) );
            ti[11] = (float)( idet * -(m00*A1312 - m01*A0312 + m03*A0112) );
        }
        __syncthreads();

        // ===== phase 2: staging, lane = half-row =====
        {
            const int rl = l & 31;          // local row 0..31
            const int pt = l >> 5;          // part: elems [pt*24, pt*24+24)
            const int br = rl >> 4;         // branch 0: (x1, T x2)  1: (x2, Tinv x1)
            const int dp = rl & 15;         // local pair
            const int p  = pbase + dp;
            const int ia = o1[p], ib = o2[p];
            const int oa = br ? ib : ia;
            const int ob = br ? ia : ib;
            ushort* xrow = xs + (w * 32 + rl) * LDX;

            // copy half (24 bf16 from pre-converted table)
            {
                const uint4* src = reinterpret_cast<const uint4*>(gbf + oa * 48 + pt * 24);
                uint4* dst = reinterpret_cast<uint4*>(xrow + pt * 24);
                dst[0] = src[0]; dst[1] = src[1]; dst[2] = src[2];
            }

            // transform half: 8 vec3s
            float4 M0, M1, M2;
            if (br == 0) {
                const float4* Tp = reinterpret_cast<const float4*>(Tg + (size_t)p * 16);
                M0 = Tp[0]; M1 = Tp[1]; M2 = Tp[2];
            } else {
                const float4* ti = reinterpret_cast<const float4*>(&tinv[(w * 16 + dp) * 16]);
                M0 = ti[0]; M1 = ti[1]; M2 = ti[2];
            }
            float v[24];
            {
                const float4* bs = reinterpret_cast<const float4*>(geoms + (size_t)ob * 48 + pt * 24);
                #pragma unroll
                for (int q = 0; q < 6; ++q) {
                    float4 t = bs[q];
                    v[4*q+0] = t.x; v[4*q+1] = t.y; v[4*q+2] = t.z; v[4*q+3] = t.w;
                }
            }
            union { ushort us[24]; uint4 q4[3]; } pk;
            #pragma unroll
            for (int m = 0; m < 8; ++m) {
                float vx = v[3*m+0], vy = v[3*m+1], vz = v[3*m+2];
                pk.us[3*m+0] = f2bf(fmaf(M0.x, vx, fmaf(M0.y, vy, fmaf(M0.z, vz, M0.w))));
                pk.us[3*m+1] = f2bf(fmaf(M1.x, vx, fmaf(M1.y, vy, fmaf(M1.z, vz, M1.w))));
                pk.us[3*m+2] = f2bf(fmaf(M2.x, vx, fmaf(M2.y, vy, fmaf(M2.z, vz, M2.w))));
            }
            uint4* dst = reinterpret_cast<uint4*>(xrow + 48 + pt * 24);
            dst[0] = pk.q4[0]; dst[1] = pk.q4[1]; dst[2] = pk.q4[2];
        }
        __syncthreads();

        // opaque per-iteration weight base: defeats LICM of the 36 fragment loads
        // (hoisting them = 144 live VGPRs = the round-3/4 scratch-spill pathology)
        uintptr_t wb = (uintptr_t)wfrag;
        asm volatile("" : "+v"(wb));
        const ushort* wfi = (const ushort*)wb;

        // ===== layer 1: acc[mt][nt] = W1-frag x x-frag (zero-init, bias in epilogue) =====
        f32x4 acc[6][2];
        #pragma unroll
        for (int mt = 0; mt < 6; ++mt) {
            acc[mt][0] = (f32x4){0.f, 0.f, 0.f, 0.f};
            acc[mt][1] = (f32x4){0.f, 0.f, 0.f, 0.f};
        }
        bf16x8 xf[2][3];
        #pragma unroll
        for (int nt = 0; nt < 2; ++nt)
            #pragma unroll
            for (int kb = 0; kb < 3; ++kb)
                xf[nt][kb] = *reinterpret_cast<const bf16x8*>(
                    xs + (w*32 + nt*16 + cl) * LDX + kb*32 + g*8);
        #pragma unroll
        for (int mt = 0; mt < 6; ++mt) {
            bf16x8 wfr[3];
            #pragma unroll
            for (int kb = 0; kb < 3; ++kb)
                wfr[kb] = *reinterpret_cast<const bf16x8*>(
                    wfi + ((size_t)((0*18 + mt*3 + kb) * 64 + l)) * 8);
            #pragma unroll
            for (int nt = 0; nt < 2; ++nt)
                #pragma unroll
                for (int kb = 0; kb < 3; ++kb)
                    acc[mt][nt] = __builtin_amdgcn_mfma_f32_16x16x32_bf16(
                        wfr[kb], xf[nt][kb], acc[mt][nt], 0, 0, 0);
        }

        // epilogue 1: +bias, relu -> bf16, b64 write (4 consecutive n_out per lane)
        #pragma unroll
        for (int mt = 0; mt < 6; ++mt) {
            float4 bv = *reinterpret_cast<const float4*>(b1 + mt*16 + rg);
            #pragma unroll
            for (int nt = 0; nt < 2; ++nt) {
                union { ushort us[4]; uint2 u2; } h4;
                h4.us[0] = f2bf(fmaxf(acc[mt][nt][0] + bv.x, 0.f));
                h4.us[1] = f2bf(fmaxf(acc[mt][nt][1] + bv.y, 0.f));
                h4.us[2] = f2bf(fmaxf(acc[mt][nt][2] + bv.z, 0.f));
                h4.us[3] = f2bf(fmaxf(acc[mt][nt][3] + bv.w, 0.f));
                *reinterpret_cast<uint2*>(
                    xs + (w*32 + nt*16 + cl) * LDX + mt*16 + rg) = h4.u2;
            }
        }

        // ===== layer 2 ===== (h-tile rows are wave-private; no barrier needed)
        f32x4 acc2[6][2];
        #pragma unroll
        for (int mt = 0; mt < 6; ++mt) {
            acc2[mt][0] = (f32x4){0.f, 0.f, 0.f, 0.f};
            acc2[mt][1] = (f32x4){0.f, 0.f, 0.f, 0.f};
        }
        bf16x8 hf[2][3];
        #pragma unroll
        for (int nt = 0; nt < 2; ++nt)
            #pragma unroll
            for (int kb = 0; kb < 3; ++kb)
                hf[nt][kb] = *reinterpret_cast<const bf16x8*>(
                    xs + (w*32 + nt*16 + cl) * LDX + kb*32 + g*8);
        #pragma unroll
        for (int mt = 0; mt < 6; ++mt) {
            bf16x8 wfr[3];
            #pragma unroll
            for (int kb = 0; kb < 3; ++kb)
                wfr[kb] = *reinterpret_cast<const bf16x8*>(
                    wfi + ((size_t)((1*18 + mt*3 + kb) * 64 + l)) * 8);
            #pragma unroll
            for (int nt = 0; nt < 2; ++nt)
                #pragma unroll
                for (int kb = 0; kb < 3; ++kb)
                    acc2[mt][nt] = __builtin_amdgcn_mfma_f32_16x16x32_bf16(
                        wfr[kb], hf[nt][kb], acc2[mt][nt], 0, 0, 0);
        }

        // epilogue 2: +bias, relu, W3 dot in-lane, 2 shuffles, coalesced store
        float pr0 = 0.f, pr1 = 0.f;
        #pragma unroll
        for (int mt = 0; mt < 6; ++mt) {
            float4 bv  = *reinterpret_cast<const float4*>(b2 + mt*16 + rg);
            float4 w3v = *reinterpret_cast<const float4*>(W3 + mt*16 + rg);
            pr0 = fmaf(fmaxf(acc2[mt][0][0] + bv.x, 0.f), w3v.x, pr0);
            pr0 = fmaf(fmaxf(acc2[mt][0][1] + bv.y, 0.f), w3v.y, pr0);
            pr0 = fmaf(fmaxf(acc2[mt][0][2] + bv.z, 0.f), w3v.z, pr0);
            pr0 = fmaf(fmaxf(acc2[mt][0][3] + bv.w, 0.f), w3v.w, pr0);
            pr1 = fmaf(fmaxf(acc2[mt][1][0] + bv.x, 0.f), w3v.x, pr1);
            pr1 = fmaf(fmaxf(acc2[mt][1][1] + bv.y, 0.f), w3v.y, pr1);
            pr1 = fmaf(fmaxf(acc2[mt][1][2] + bv.z, 0.f), w3v.z, pr1);
            pr1 = fmaf(fmaxf(acc2[mt][1][3] + bv.w, 0.f), w3v.w, pr1);
        }
        pr0 += __shfl_xor(pr0, 16, 64);
        pr0 += __shfl_xor(pr0, 32, 64);
        pr1 += __shfl_xor(pr1, 16, 64);
        pr1 += __shfl_xor(pr1, 32, 64);
        if (l < 16)
            out[pbase + l] = 0.5f * (pr0 + pr1) + b3[0];
    }
}

extern "C" void kernel_launch(void* const* d_in, const int* in_sizes, int n_in,
                              void* d_out, int out_size, void* d_ws, size_t ws_size,
                              hipStream_t stream) {
    const int*   o1    = (const int*)d_in[0];
    const int*   o2    = (const int*)d_in[1];
    const float* T     = (const float*)d_in[2];
    const float* geoms = (const float*)d_in[3];
    const float* W1    = (const float*)d_in[4];
    const float* b1    = (const float*)d_in[5];
    const float* W2    = (const float*)d_in[6];
    const float* b2    = (const float*)d_in[7];
    const float* W3    = (const float*)d_in[8];
    const float* b3    = (const float*)d_in[9];
    float* out = (float*)d_out;
    const int N  = in_sizes[0];
    const int NG = in_sizes[3];           // 48000

    ushort* wfr = (ushort*)d_ws;
    ushort* gbf = wfr + WFRAG_USHORTS;

    hipLaunchKernelGGL(prep_wfrag, dim3((36 * 64 + 255) / 256), dim3(256), 0, stream,
                       W1, W2, wfr);
    hipLaunchKernelGGL(prep_geoms, dim3((NG + 255) / 256), dim3(256), 0, stream,
                       geoms, gbf, NG);
    hipLaunchKernelGGL(collision_mfma, dim3(NBLK), dim3(BT), 0, stream,
                       o1, o2, T, geoms, gbf, wfr, b1, b2, W3, b3, out, N);
}

// Round 7
// 164.267 us; speedup vs baseline: 1.2509x; 1.2509x over previous
//
#include <hip/hip_runtime.h>

typedef __attribute__((ext_vector_type(8))) short bf16x8;
typedef __attribute__((ext_vector_type(4))) float f32x4;

constexpr int BT   = 256;   // threads/block (4 waves)
constexpr int TP   = 64;    // pairs per tile (16 per wave)
constexpr int KD   = 96;    // feature/hidden dim
constexpr int LDX  = 104;   // row stride in bf16 (208 B: 16B-aligned)
constexpr int LDT  = 20;    // tinv stride in floats (80 B: float4-aligned, 2-way banks)
constexpr int NBLK = 512;   // persistent blocks (2 per CU)

__device__ inline ushort f2bf(float f) {  // fp32 -> bf16 RNE
    uint u = __float_as_uint(f);
    u += 0x7fffu + ((u >> 16) & 1u);
    return (ushort)(u >> 16);
}

// prep: geoms f32 -> bf16 table in d_ws
__global__ void prep_geoms(const float* __restrict__ g, ushort* __restrict__ gb, int n) {
    int i = blockIdx.x * 256 + threadIdx.x;
    if (i < n) gb[i] = f2bf(g[i]);
}

__global__ void __launch_bounds__(BT, 2) collision_mfma(
    const int* __restrict__ o1, const int* __restrict__ o2,
    const float* __restrict__ Tg, const float* __restrict__ geoms,
    const ushort* __restrict__ gbf,
    const float* __restrict__ W1, const float* __restrict__ b1,
    const float* __restrict__ W2, const float* __restrict__ b2,
    const float* __restrict__ W3, const float* __restrict__ b3,
    float* __restrict__ out, int N)
{
    __shared__ ushort xs[128 * LDX];    // x/h tile bf16, wave-private 32-row bands
    __shared__ ushort w1t[KD * LDX];    // W1^T bf16 [n][k]
    __shared__ ushort w2t[KD * LDX];    // W2^T bf16 [n][k]
    __shared__ float  tinv[64 * LDT];   // per-pair inverse rows 0..2 (wave-private)

    const int tid = threadIdx.x;
    const int w   = tid >> 6;      // wave 0..3
    const int l   = tid & 63;      // lane
    const int cl  = l & 15;        // fragment col within 16-tile
    const int g   = l >> 4;        // k-group 0..3
    const int rg  = g * 4;

    // ---- stage weights once: wt[n][k] = W[k][n], bf16 ----
    for (int i = tid; i < KD * KD; i += BT) {
        int k = i / KD;
        int n = i - k * KD;
        w1t[n * LDX + k] = f2bf(W1[i]);
        w2t[n * LDX + k] = f2bf(W2[i]);
    }
    __syncthreads();   // only runtime barrier: weights ready for all waves

    const int ntiles = N / TP;

    // Main loop is entirely wave-private (tinv/xs bands/outputs per wave), so no
    // runtime barriers. asm memory fences at phase boundaries stop LICM from
    // hoisting the 36 loop-invariant weight ds_reads (144 VGPRs = round-3/4 spill).
    for (int tile = blockIdx.x; tile < ntiles; tile += NBLK) {
        const int pbase = tile * TP + w * 16;

        // ===== phase 1: f64 4x4 inverse, lanes 0..15, one pair each =====
        if (l < 16) {
            const int p = pbase + l;
            const float4* T4 = reinterpret_cast<const float4*>(Tg + (size_t)p * 16);
            float4 t0 = T4[0], t1 = T4[1], t2 = T4[2], t3 = T4[3];
            double m00=t0.x, m01=t0.y, m02=t0.z, m03=t0.w;
            double m10=t1.x, m11=t1.y, m12=t1.z, m13=t1.w;
            double m20=t2.x, m21=t2.y, m22=t2.z, m23=t2.w;
            double m30=t3.x, m31=t3.y, m32=t3.z, m33=t3.w;
            double A2323 = m22*m33 - m23*m32;
            double A1323 = m21*m33 - m23*m31;
            double A1223 = m21*m32 - m22*m31;
            double A0323 = m20*m33 - m23*m30;
            double A0223 = m20*m32 - m22*m30;
            double A0123 = m20*m31 - m21*m30;
            double A2313 = m12*m33 - m13*m32;
            double A1313 = m11*m33 - m13*m31;
            double A1213 = m11*m32 - m12*m31;
            double A2312 = m12*m23 - m13*m22;
            double A1312 = m11*m23 - m13*m21;
            double A1212 = m11*m22 - m12*m21;
            double A0313 = m10*m33 - m13*m30;
            double A0213 = m10*m32 - m12*m30;
            double A0312 = m10*m23 - m13*m20;
            double A0212 = m10*m22 - m12*m20;
            double A0113 = m10*m31 - m11*m30;
            double A0112 = m10*m21 - m11*m20;
            double det = m00*(m11*A2323 - m12*A1323 + m13*A1223)
                       - m01*(m10*A2323 - m12*A0323 + m13*A0223)
                       + m02*(m10*A1323 - m11*A0323 + m13*A0123)
                       - m03*(m10*A1223 - m11*A0223 + m12*A0123);
            double idet = 1.0 / det;
            float* ti = &tinv[(w * 16 + l) * LDT];
            ti[0]  = (float)( idet *  (m11*A2323 - m12*A1323 + m13*A1223) );
            ti[1]  = (float)( idet * -(m01*A2323 - m02*A1323 + m03*A1223) );
            ti[2]  = (float)( idet *  (m01*A2313 - m02*A1313 + m03*A1213) );
            ti[3]  = (float)( idet * -(m01*A2312 - m02*A1312 + m03*A1212) );
            ti[4]  = (float)( idet * -(m10*A2323 - m12*A0323 + m13*A0223) );
            ti[5]  = (float)( idet *  (m00*A2323 - m02*A0323 + m03*A0223) );
            ti[6]  = (float)( idet * -(m00*A2313 - m02*A0313 + m03*A0213) );
            ti[7]  = (float)( idet *  (m00*A2312 - m02*A0312 + m03*A0212) );
            ti[8]  = (float)( idet *  (m10*A1323 - m11*A0323 + m13*A0123) );
            ti[9]  = (float)( idet * -(m00*A1323 - m01*A0323 + m03*A0123) );
            ti[10] = (float)( idet *  (m00*A1313 - m01*A0313 + m03*A0113) );
            ti[11] = (float)( idet * -(m00*A1312 - m01*A0312 + m03*A0112) );
        }
        asm volatile("" ::: "memory");   // fence (in-wave DS order gives correctness)

        // ===== phase 2: staging, lane = half-row =====
        {
            const int rl = l & 31;          // local row 0..31
            const int pt = l >> 5;          // part: elems [pt*24, pt*24+24)
            const int br = rl >> 4;         // branch 0: (x1, T x2)  1: (x2, Tinv x1)
            const int dp = rl & 15;         // local pair
            const int p  = pbase + dp;
            const int ia = o1[p], ib = o2[p];
            const int oa = br ? ib : ia;
            const int ob = br ? ia : ib;
            ushort* xrow = xs + (w * 32 + rl) * LDX;

            // copy half (24 bf16 from pre-converted table)
            {
                const uint4* src = reinterpret_cast<const uint4*>(gbf + oa * 48 + pt * 24);
                uint4* dst = reinterpret_cast<uint4*>(xrow + pt * 24);
                dst[0] = src[0]; dst[1] = src[1]; dst[2] = src[2];
            }

            // transform half: 8 vec3s
            float4 M0, M1, M2;
            if (br == 0) {
                const float4* Tp = reinterpret_cast<const float4*>(Tg + (size_t)p * 16);
                M0 = Tp[0]; M1 = Tp[1]; M2 = Tp[2];
            } else {
                const float4* ti = reinterpret_cast<const float4*>(&tinv[(w * 16 + dp) * LDT]);
                M0 = ti[0]; M1 = ti[1]; M2 = ti[2];
            }
            float v[24];
            {
                const float4* bs = reinterpret_cast<const float4*>(geoms + (size_t)ob * 48 + pt * 24);
                #pragma unroll
                for (int q = 0; q < 6; ++q) {
                    float4 t = bs[q];
                    v[4*q+0] = t.x; v[4*q+1] = t.y; v[4*q+2] = t.z; v[4*q+3] = t.w;
                }
            }
            union { ushort us[24]; uint4 q4[3]; } pk;
            #pragma unroll
            for (int m = 0; m < 8; ++m) {
                float vx = v[3*m+0], vy = v[3*m+1], vz = v[3*m+2];
                pk.us[3*m+0] = f2bf(fmaf(M0.x, vx, fmaf(M0.y, vy, fmaf(M0.z, vz, M0.w))));
                pk.us[3*m+1] = f2bf(fmaf(M1.x, vx, fmaf(M1.y, vy, fmaf(M1.z, vz, M1.w))));
                pk.us[3*m+2] = f2bf(fmaf(M2.x, vx, fmaf(M2.y, vy, fmaf(M2.z, vz, M2.w))));
            }
            uint4* dst = reinterpret_cast<uint4*>(xrow + 48 + pt * 24);
            dst[0] = pk.q4[0]; dst[1] = pk.q4[1]; dst[2] = pk.q4[2];
        }
        asm volatile("" ::: "memory");   // fence: stop LICM of weight ds_reads

        // ===== layer 1: acc[mt][nt] = W1^T-frag x x-frag (zero-init, bias in epilogue) =====
        f32x4 acc[6][2];
        #pragma unroll
        for (int mt = 0; mt < 6; ++mt) {
            acc[mt][0] = (f32x4){0.f, 0.f, 0.f, 0.f};
            acc[mt][1] = (f32x4){0.f, 0.f, 0.f, 0.f};
        }
        bf16x8 xf[2][3];
        #pragma unroll
        for (int nt = 0; nt < 2; ++nt)
            #pragma unroll
            for (int kb = 0; kb < 3; ++kb)
                xf[nt][kb] = *reinterpret_cast<const bf16x8*>(
                    xs + (w*32 + nt*16 + cl) * LDX + kb*32 + g*8);
        #pragma unroll
        for (int mt = 0; mt < 6; ++mt) {
            bf16x8 wfr[3];
            #pragma unroll
            for (int kb = 0; kb < 3; ++kb)
                wfr[kb] = *reinterpret_cast<const bf16x8*>(
                    w1t + (mt*16 + cl) * LDX + kb*32 + g*8);
            #pragma unroll
            for (int nt = 0; nt < 2; ++nt)
                #pragma unroll
                for (int kb = 0; kb < 3; ++kb)
                    acc[mt][nt] = __builtin_amdgcn_mfma_f32_16x16x32_bf16(
                        wfr[kb], xf[nt][kb], acc[mt][nt], 0, 0, 0);
        }

        // epilogue 1: +bias, relu -> bf16, b64 write (4 consecutive n_out per lane)
        #pragma unroll
        for (int mt = 0; mt < 6; ++mt) {
            float4 bv = *reinterpret_cast<const float4*>(b1 + mt*16 + rg);
            #pragma unroll
            for (int nt = 0; nt < 2; ++nt) {
                union { ushort us[4]; uint2 u2; } h4;
                h4.us[0] = f2bf(fmaxf(acc[mt][nt][0] + bv.x, 0.f));
                h4.us[1] = f2bf(fmaxf(acc[mt][nt][1] + bv.y, 0.f));
                h4.us[2] = f2bf(fmaxf(acc[mt][nt][2] + bv.z, 0.f));
                h4.us[3] = f2bf(fmaxf(acc[mt][nt][3] + bv.w, 0.f));
                *reinterpret_cast<uint2*>(
                    xs + (w*32 + nt*16 + cl) * LDX + mt*16 + rg) = h4.u2;
            }
        }
        asm volatile("" ::: "memory");   // fence between layers

        // ===== layer 2 =====
        f32x4 acc2[6][2];
        #pragma unroll
        for (int mt = 0; mt < 6; ++mt) {
            acc2[mt][0] = (f32x4){0.f, 0.f, 0.f, 0.f};
            acc2[mt][1] = (f32x4){0.f, 0.f, 0.f, 0.f};
        }
        bf16x8 hf[2][3];
        #pragma unroll
        for (int nt = 0; nt < 2; ++nt)
            #pragma unroll
            for (int kb = 0; kb < 3; ++kb)
                hf[nt][kb] = *reinterpret_cast<const bf16x8*>(
                    xs + (w*32 + nt*16 + cl) * LDX + kb*32 + g*8);
        #pragma unroll
        for (int mt = 0; mt < 6; ++mt) {
            bf16x8 wfr[3];
            #pragma unroll
            for (int kb = 0; kb < 3; ++kb)
                wfr[kb] = *reinterpret_cast<const bf16x8*>(
                    w2t + (mt*16 + cl) * LDX + kb*32 + g*8);
            #pragma unroll
            for (int nt = 0; nt < 2; ++nt)
                #pragma unroll
                for (int kb = 0; kb < 3; ++kb)
                    acc2[mt][nt] = __builtin_amdgcn_mfma_f32_16x16x32_bf16(
                        wfr[kb], hf[nt][kb], acc2[mt][nt], 0, 0, 0);
        }

        // epilogue 2: +bias, relu, W3 dot in-lane, 2 shuffles, coalesced store
        float pr0 = 0.f, pr1 = 0.f;
        #pragma unroll
        for (int mt = 0; mt < 6; ++mt) {
            float4 bv  = *reinterpret_cast<const float4*>(b2 + mt*16 + rg);
            float4 w3v = *reinterpret_cast<const float4*>(W3 + mt*16 + rg);
            pr0 = fmaf(fmaxf(acc2[mt][0][0] + bv.x, 0.f), w3v.x, pr0);
            pr0 = fmaf(fmaxf(acc2[mt][0][1] + bv.y, 0.f), w3v.y, pr0);
            pr0 = fmaf(fmaxf(acc2[mt][0][2] + bv.z, 0.f), w3v.z, pr0);
            pr0 = fmaf(fmaxf(acc2[mt][0][3] + bv.w, 0.f), w3v.w, pr0);
            pr1 = fmaf(fmaxf(acc2[mt][1][0] + bv.x, 0.f), w3v.x, pr1);
            pr1 = fmaf(fmaxf(acc2[mt][1][1] + bv.y, 0.f), w3v.y, pr1);
            pr1 = fmaf(fmaxf(acc2[mt][1][2] + bv.z, 0.f), w3v.z, pr1);
            pr1 = fmaf(fmaxf(acc2[mt][1][3] + bv.w, 0.f), w3v.w, pr1);
        }
        pr0 += __shfl_xor(pr0, 16, 64);
        pr0 += __shfl_xor(pr0, 32, 64);
        pr1 += __shfl_xor(pr1, 16, 64);
        pr1 += __shfl_xor(pr1, 32, 64);
        if (l < 16)
            out[pbase + l] = 0.5f * (pr0 + pr1) + b3[0];

        asm volatile("" ::: "memory");   // fence at loop end
    }
}

extern "C" void kernel_launch(void* const* d_in, const int* in_sizes, int n_in,
                              void* d_out, int out_size, void* d_ws, size_t ws_size,
                              hipStream_t stream) {
    const int*   o1    = (const int*)d_in[0];
    const int*   o2    = (const int*)d_in[1];
    const float* T     = (const float*)d_in[2];
    const float* geoms = (const float*)d_in[3];
    const float* W1    = (const float*)d_in[4];
    const float* b1    = (const float*)d_in[5];
    const float* W2    = (const float*)d_in[6];
    const float* b2    = (const float*)d_in[7];
    const float* W3    = (const float*)d_in[8];
    const float* b3    = (const float*)d_in[9];
    float* out = (float*)d_out;
    const int N  = in_sizes[0];
    const int NG = in_sizes[3];           // 48000

    ushort* gbf = (ushort*)d_ws;
    hipLaunchKernelGGL(prep_geoms, dim3((NG + 255) / 256), dim3(256), 0, stream,
                       geoms, gbf, NG);
    hipLaunchKernelGGL(collision_mfma, dim3(NBLK), dim3(BT), 0, stream,
                       o1, o2, T, geoms, gbf, W1, b1, W2, b2, W3, b3, out, N);
}

// Round 8
// 161.902 us; speedup vs baseline: 1.2692x; 1.0146x over previous
//
#include <hip/hip_runtime.h>

typedef __attribute__((ext_vector_type(8))) short bf16x8;
typedef __attribute__((ext_vector_type(4))) float f32x4;

constexpr int BT   = 256;   // threads/block (4 waves)
constexpr int TP   = 64;    // pairs per tile (16 per wave)
constexpr int KD   = 96;    // feature/hidden dim
constexpr int LDW  = 104;   // weight LDS row stride (bf16): 208 B, min-conflict
constexpr int LDXX = 120;   // xs LDS row stride (bf16): 240 B, conflict-free staging
constexpr int LDT  = 20;    // tinv stride (floats)
constexpr int NBLK = 512;   // persistent blocks (2 per CU)

__device__ inline ushort f2bf(float f) {  // fp32 -> bf16 RNE
    uint u = __float_as_uint(f);
    u += 0x7fffu + ((u >> 16) & 1u);
    return (ushort)(u >> 16);
}

// prep: geoms f32 -> bf16 table in d_ws
__global__ void prep_geoms(const float* __restrict__ g, ushort* __restrict__ gb, int n) {
    int i = blockIdx.x * 256 + threadIdx.x;
    if (i < n) gb[i] = f2bf(g[i]);
}

// f64 adjugate 4x4 inverse; writes rows 0..2 (3x4 floats) to ti
__device__ inline void inv4x4(float4 t0, float4 t1, float4 t2, float4 t3,
                              float* __restrict__ ti) {
    double m00=t0.x, m01=t0.y, m02=t0.z, m03=t0.w;
    double m10=t1.x, m11=t1.y, m12=t1.z, m13=t1.w;
    double m20=t2.x, m21=t2.y, m22=t2.z, m23=t2.w;
    double m30=t3.x, m31=t3.y, m32=t3.z, m33=t3.w;
    double A2323 = m22*m33 - m23*m32;
    double A1323 = m21*m33 - m23*m31;
    double A1223 = m21*m32 - m22*m31;
    double A0323 = m20*m33 - m23*m30;
    double A0223 = m20*m32 - m22*m30;
    double A0123 = m20*m31 - m21*m30;
    double A2313 = m12*m33 - m13*m32;
    double A1313 = m11*m33 - m13*m31;
    double A1213 = m11*m32 - m12*m31;
    double A2312 = m12*m23 - m13*m22;
    double A1312 = m11*m23 - m13*m21;
    double A1212 = m11*m22 - m12*m21;
    double A0313 = m10*m33 - m13*m30;
    double A0213 = m10*m32 - m12*m30;
    double A0312 = m10*m23 - m13*m20;
    double A0212 = m10*m22 - m12*m20;
    double A0113 = m10*m31 - m11*m30;
    double A0112 = m10*m21 - m11*m20;
    double det = m00*(m11*A2323 - m12*A1323 + m13*A1223)
               - m01*(m10*A2323 - m12*A0323 + m13*A0223)
               + m02*(m10*A1323 - m11*A0323 + m13*A0123)
               - m03*(m10*A1223 - m11*A0223 + m12*A0123);
    double idet = 1.0 / det;
    ti[0]  = (float)( idet *  (m11*A2323 - m12*A1323 + m13*A1223) );
    ti[1]  = (float)( idet * -(m01*A2323 - m02*A1323 + m03*A1223) );
    ti[2]  = (float)( idet *  (m01*A2313 - m02*A1313 + m03*A1213) );
    ti[3]  = (float)( idet * -(m01*A2312 - m02*A1312 + m03*A1212) );
    ti[4]  = (float)( idet * -(m10*A2323 - m12*A0323 + m13*A0223) );
    ti[5]  = (float)( idet *  (m00*A2323 - m02*A0323 + m03*A0223) );
    ti[6]  = (float)( idet * -(m00*A2313 - m02*A0313 + m03*A0213) );
    ti[7]  = (float)( idet *  (m00*A2312 - m02*A0312 + m03*A0212) );
    ti[8]  = (float)( idet *  (m10*A1323 - m11*A0323 + m13*A0123) );
    ti[9]  = (float)( idet * -(m00*A1323 - m01*A0323 + m03*A0123) );
    ti[10] = (float)( idet *  (m00*A1313 - m01*A0313 + m03*A0113) );
    ti[11] = (float)( idet * -(m00*A1312 - m01*A0312 + m03*A0112) );
}

__global__ void __launch_bounds__(BT, 2) collision_mfma(
    const int* __restrict__ o1, const int* __restrict__ o2,
    const float* __restrict__ Tg, const float* __restrict__ geoms,
    const ushort* __restrict__ gbf,
    const float* __restrict__ W1, const float* __restrict__ b1,
    const float* __restrict__ W2, const float* __restrict__ b2,
    const float* __restrict__ W3, const float* __restrict__ b3,
    float* __restrict__ out, int N)
{
    __shared__ ushort xs[128 * LDXX];   // x/h tile bf16, wave-private 32-row bands
    __shared__ ushort w1t[KD * LDW];    // W1^T bf16 [n][k]
    __shared__ ushort w2t[KD * LDW];    // W2^T bf16 [n][k]
    __shared__ float  tinv[64 * LDT];   // per-pair inverse rows 0..2 (wave-private)

    const int tid = threadIdx.x;
    const int w   = tid >> 6;      // wave 0..3
    const int l   = tid & 63;      // lane
    const int cl  = l & 15;        // fragment col within 16-tile
    const int g   = l >> 4;        // k-group 0..3
    const int rg  = g * 4;

    // staging roles (fixed per lane)
    const int rl = l & 31;         // local row 0..31
    const int pt = l >> 5;         // part: elems [pt*24, pt*24+24)
    const int br = rl >> 4;        // branch 0: (x1, T x2)  1: (x2, Tinv x1)
    const int dp = rl & 15;        // local pair

    // ---- stage weights once: wt[n][k] = W[k][n], bf16 ----
    for (int i = tid; i < KD * KD; i += BT) {
        int k = i / KD;
        int n = i - k * KD;
        w1t[n * LDW + k] = f2bf(W1[i]);
        w2t[n * LDW + k] = f2bf(W2[i]);
    }
    __syncthreads();   // only runtime barrier

    const int ntiles = N / TP;
    int tile = blockIdx.x;

    // ================= prologue: fill the pipeline for tile0 =================
    float4 RT0, RT1, RT2;              // T rows 0..2 for this lane's pair (br==0)
    uint4  RC0, RC1, RC2;              // copy-half bf16 data
    float4 RV0, RV1, RV2, RV3, RV4, RV5; // transform-half f32 data
    int iaN = 0, ibN = 0;              // idx for tile+NBLK (feeds next prefetch)
    {
        const int pb0 = tile * TP + w * 16;
        const int p0  = pb0 + dp;
        int iaC = o1[p0], ibC = o2[p0];
        float4 A0, A1, A2, A3;
        if (l < 16) {
            const float4* T4 = reinterpret_cast<const float4*>(Tg + (size_t)(pb0 + l) * 16);
            A0 = T4[0]; A1 = T4[1]; A2 = T4[2]; A3 = T4[3];
        }
        if (br == 0) {
            const float4* Tp = reinterpret_cast<const float4*>(Tg + (size_t)p0 * 16);
            RT0 = Tp[0]; RT1 = Tp[1]; RT2 = Tp[2];
        }
        int oa = br ? ibC : iaC, ob = br ? iaC : ibC;
        const uint4* cs = reinterpret_cast<const uint4*>(gbf + oa * 48 + pt * 24);
        RC0 = cs[0]; RC1 = cs[1]; RC2 = cs[2];
        const float4* vs = reinterpret_cast<const float4*>(geoms + (size_t)ob * 48 + pt * 24);
        RV0 = vs[0]; RV1 = vs[1]; RV2 = vs[2]; RV3 = vs[3]; RV4 = vs[4]; RV5 = vs[5];
        int t1 = tile + NBLK;
        if (t1 < ntiles) {
            int p1 = t1 * TP + w * 16 + dp;
            iaN = o1[p1]; ibN = o2[p1];
        }
        if (l < 16) inv4x4(A0, A1, A2, A3, &tinv[(w * 16 + l) * LDT]);
    }

    // ================= main loop: 1-deep pipelined =================
    for (; tile < ntiles; tile += NBLK) {
        const int pbase = tile * TP + w * 16;

        // ---- staging for current tile (all from registers + tinv) ----
        {
            ushort* xrow = xs + (w * 32 + rl) * LDXX;
            uint4* dstc = reinterpret_cast<uint4*>(xrow + pt * 24);
            dstc[0] = RC0; dstc[1] = RC1; dstc[2] = RC2;

            float4 M0, M1, M2;
            if (br == 0) { M0 = RT0; M1 = RT1; M2 = RT2; }
            else {
                const float4* ti = reinterpret_cast<const float4*>(&tinv[(w * 16 + dp) * LDT]);
                M0 = ti[0]; M1 = ti[1]; M2 = ti[2];
            }
            float v[24];
            v[0]=RV0.x; v[1]=RV0.y; v[2]=RV0.z; v[3]=RV0.w;
            v[4]=RV1.x; v[5]=RV1.y; v[6]=RV1.z; v[7]=RV1.w;
            v[8]=RV2.x; v[9]=RV2.y; v[10]=RV2.z; v[11]=RV2.w;
            v[12]=RV3.x; v[13]=RV3.y; v[14]=RV3.z; v[15]=RV3.w;
            v[16]=RV4.x; v[17]=RV4.y; v[18]=RV4.z; v[19]=RV4.w;
            v[20]=RV5.x; v[21]=RV5.y; v[22]=RV5.z; v[23]=RV5.w;
            union { ushort us[24]; uint4 q4[3]; } pk;
            #pragma unroll
            for (int m = 0; m < 8; ++m) {
                float vx = v[3*m+0], vy = v[3*m+1], vz = v[3*m+2];
                pk.us[3*m+0] = f2bf(fmaf(M0.x, vx, fmaf(M0.y, vy, fmaf(M0.z, vz, M0.w))));
                pk.us[3*m+1] = f2bf(fmaf(M1.x, vx, fmaf(M1.y, vy, fmaf(M1.z, vz, M1.w))));
                pk.us[3*m+2] = f2bf(fmaf(M2.x, vx, fmaf(M2.y, vy, fmaf(M2.z, vz, M2.w))));
            }
            uint4* dstt = reinterpret_cast<uint4*>(xrow + 48 + pt * 24);
            dstt[0] = pk.q4[0]; dstt[1] = pk.q4[1]; dstt[2] = pk.q4[2];
        }

        // ---- issue prefetch for tile+NBLK (latency hides under MFMA below) ----
        const int tn  = tile + NBLK;
        const bool h1 = tn < ntiles;
        const int tn2 = tile + 2 * NBLK;
        const bool h2 = tn2 < ntiles;
        float4 B0, B1, B2, B3;
        float4 RT0n, RT1n, RT2n;
        uint4  RC0n, RC1n, RC2n;
        float4 RV0n, RV1n, RV2n, RV3n, RV4n, RV5n;
        int iaN2 = 0, ibN2 = 0;
        if (h1) {
            const int pbn = tn * TP + w * 16;
            const int pn  = pbn + dp;
            if (l < 16) {
                const float4* T4 = reinterpret_cast<const float4*>(Tg + (size_t)(pbn + l) * 16);
                B0 = T4[0]; B1 = T4[1]; B2 = T4[2]; B3 = T4[3];
            }
            if (br == 0) {
                const float4* Tp = reinterpret_cast<const float4*>(Tg + (size_t)pn * 16);
                RT0n = Tp[0]; RT1n = Tp[1]; RT2n = Tp[2];
            }
            int oan = br ? ibN : iaN, obn = br ? iaN : ibN;
            const uint4* cs = reinterpret_cast<const uint4*>(gbf + oan * 48 + pt * 24);
            RC0n = cs[0]; RC1n = cs[1]; RC2n = cs[2];
            const float4* vs = reinterpret_cast<const float4*>(geoms + (size_t)obn * 48 + pt * 24);
            RV0n = vs[0]; RV1n = vs[1]; RV2n = vs[2]; RV3n = vs[3]; RV4n = vs[4]; RV5n = vs[5];
        }
        if (h2) {
            int p2 = tn2 * TP + w * 16 + dp;
            iaN2 = o1[p2]; ibN2 = o2[p2];
        }
        asm volatile("" ::: "memory");   // fence: stop LICM of weight ds_reads

        // ===== layer 1 =====
        f32x4 acc[6][2];
        #pragma unroll
        for (int mt = 0; mt < 6; ++mt) {
            acc[mt][0] = (f32x4){0.f, 0.f, 0.f, 0.f};
            acc[mt][1] = (f32x4){0.f, 0.f, 0.f, 0.f};
        }
        bf16x8 xf[2][3];
        #pragma unroll
        for (int nt = 0; nt < 2; ++nt)
            #pragma unroll
            for (int kb = 0; kb < 3; ++kb)
                xf[nt][kb] = *reinterpret_cast<const bf16x8*>(
                    xs + (w*32 + nt*16 + cl) * LDXX + kb*32 + g*8);
        #pragma unroll
        for (int mt = 0; mt < 6; ++mt) {
            bf16x8 wfr[3];
            #pragma unroll
            for (int kb = 0; kb < 3; ++kb)
                wfr[kb] = *reinterpret_cast<const bf16x8*>(
                    w1t + (mt*16 + cl) * LDW + kb*32 + g*8);
            #pragma unroll
            for (int nt = 0; nt < 2; ++nt)
                #pragma unroll
                for (int kb = 0; kb < 3; ++kb)
                    acc[mt][nt] = __builtin_amdgcn_mfma_f32_16x16x32_bf16(
                        wfr[kb], xf[nt][kb], acc[mt][nt], 0, 0, 0);
        }

        // epilogue 1: +bias, relu -> bf16, b64 write
        #pragma unroll
        for (int mt = 0; mt < 6; ++mt) {
            float4 bv = *reinterpret_cast<const float4*>(b1 + mt*16 + rg);
            #pragma unroll
            for (int nt = 0; nt < 2; ++nt) {
                union { ushort us[4]; uint2 u2; } h4;
                h4.us[0] = f2bf(fmaxf(acc[mt][nt][0] + bv.x, 0.f));
                h4.us[1] = f2bf(fmaxf(acc[mt][nt][1] + bv.y, 0.f));
                h4.us[2] = f2bf(fmaxf(acc[mt][nt][2] + bv.z, 0.f));
                h4.us[3] = f2bf(fmaxf(acc[mt][nt][3] + bv.w, 0.f));
                *reinterpret_cast<uint2*>(
                    xs + (w*32 + nt*16 + cl) * LDXX + mt*16 + rg) = h4.u2;
            }
        }
        asm volatile("" ::: "memory");   // fence between layers

        // ===== layer 2 =====
        f32x4 acc2[6][2];
        #pragma unroll
        for (int mt = 0; mt < 6; ++mt) {
            acc2[mt][0] = (f32x4){0.f, 0.f, 0.f, 0.f};
            acc2[mt][1] = (f32x4){0.f, 0.f, 0.f, 0.f};
        }
        bf16x8 hf[2][3];
        #pragma unroll
        for (int nt = 0; nt < 2; ++nt)
            #pragma unroll
            for (int kb = 0; kb < 3; ++kb)
                hf[nt][kb] = *reinterpret_cast<const bf16x8*>(
                    xs + (w*32 + nt*16 + cl) * LDXX + kb*32 + g*8);
        #pragma unroll
        for (int mt = 0; mt < 6; ++mt) {
            bf16x8 wfr[3];
            #pragma unroll
            for (int kb = 0; kb < 3; ++kb)
                wfr[kb] = *reinterpret_cast<const bf16x8*>(
                    w2t + (mt*16 + cl) * LDW + kb*32 + g*8);
            #pragma unroll
            for (int nt = 0; nt < 2; ++nt)
                #pragma unroll
                for (int kb = 0; kb < 3; ++kb)
                    acc2[mt][nt] = __builtin_amdgcn_mfma_f32_16x16x32_bf16(
                        wfr[kb], hf[nt][kb], acc2[mt][nt], 0, 0, 0);
        }

        // epilogue 2: +bias, relu, W3 dot, 2 shuffles, coalesced store
        float pr0 = 0.f, pr1 = 0.f;
        #pragma unroll
        for (int mt = 0; mt < 6; ++mt) {
            float4 bv  = *reinterpret_cast<const float4*>(b2 + mt*16 + rg);
            float4 w3v = *reinterpret_cast<const float4*>(W3 + mt*16 + rg);
            pr0 = fmaf(fmaxf(acc2[mt][0][0] + bv.x, 0.f), w3v.x, pr0);
            pr0 = fmaf(fmaxf(acc2[mt][0][1] + bv.y, 0.f), w3v.y, pr0);
            pr0 = fmaf(fmaxf(acc2[mt][0][2] + bv.z, 0.f), w3v.z, pr0);
            pr0 = fmaf(fmaxf(acc2[mt][0][3] + bv.w, 0.f), w3v.w, pr0);
            pr1 = fmaf(fmaxf(acc2[mt][1][0] + bv.x, 0.f), w3v.x, pr1);
            pr1 = fmaf(fmaxf(acc2[mt][1][1] + bv.y, 0.f), w3v.y, pr1);
            pr1 = fmaf(fmaxf(acc2[mt][1][2] + bv.z, 0.f), w3v.z, pr1);
            pr1 = fmaf(fmaxf(acc2[mt][1][3] + bv.w, 0.f), w3v.w, pr1);
        }
        pr0 += __shfl_xor(pr0, 16, 64);
        pr0 += __shfl_xor(pr0, 32, 64);
        pr1 += __shfl_xor(pr1, 16, 64);
        pr1 += __shfl_xor(pr1, 32, 64);
        if (l < 16)
            out[pbase + l] = 0.5f * (pr0 + pr1) + b3[0];

        // ---- retire pipeline: inverse for next tile, rotate registers ----
        if (h1) {
            if (l < 16) inv4x4(B0, B1, B2, B3, &tinv[(w * 16 + l) * LDT]);
            RT0 = RT0n; RT1 = RT1n; RT2 = RT2n;
            RC0 = RC0n; RC1 = RC1n; RC2 = RC2n;
            RV0 = RV0n; RV1 = RV1n; RV2 = RV2n;
            RV3 = RV3n; RV4 = RV4n; RV5 = RV5n;
            iaN = iaN2; ibN = ibN2;
        }
        asm volatile("" ::: "memory");   // fence at loop end
    }
}

extern "C" void kernel_launch(void* const* d_in, const int* in_sizes, int n_in,
                              void* d_out, int out_size, void* d_ws, size_t ws_size,
                              hipStream_t stream) {
    const int*   o1    = (const int*)d_in[0];
    const int*   o2    = (const int*)d_in[1];
    const float* T     = (const float*)d_in[2];
    const float* geoms = (const float*)d_in[3];
    const float* W1    = (const float*)d_in[4];
    const float* b1    = (const float*)d_in[5];
    const float* W2    = (const float*)d_in[6];
    const float* b2    = (const float*)d_in[7];
    const float* W3    = (const float*)d_in[8];
    const float* b3    = (const float*)d_in[9];
    float* out = (float*)d_out;
    const int N  = in_sizes[0];
    const int NG = in_sizes[3];           // 48000

    ushort* gbf = (ushort*)d_ws;
    hipLaunchKernelGGL(prep_geoms, dim3((NG + 255) / 256), dim3(256), 0, stream,
                       geoms, gbf, NG);
    hipLaunchKernelGGL(collision_mfma, dim3(NBLK), dim3(BT), 0, stream,
                       o1, o2, T, geoms, gbf, W1, b1, W2, b2, W3, b3, out, N);
}

// Round 9
// 136.813 us; speedup vs baseline: 1.5019x; 1.1834x over previous
//
#include <hip/hip_runtime.h>
#include <hip/hip_bf16.h>

typedef __attribute__((ext_vector_type(8))) short bf16x8;
typedef __attribute__((ext_vector_type(4))) float f32x4;

constexpr int BT   = 1024;  // threads/block (16 waves, 1 block/CU)
constexpr int KD   = 96;    // feature/hidden dim
constexpr int LDX  = 104;   // LDS row stride in bf16 (208 B, 16B-aligned)
constexpr int LDT  = 12;    // tinv stride in floats (48 B, 16B-aligned)
constexpr int NBLK = 256;   // persistent blocks (1 per CU)
constexpr int TOTW = NBLK * (BT / 64);   // 4096 waves in flight

__device__ inline ushort f2bf(float f) {  // fp32 -> bf16 RNE (prep/weights only)
    uint u = __float_as_uint(f);
    u += 0x7fffu + ((u >> 16) & 1u);
    return (ushort)(u >> 16);
}

__device__ inline uint f2bf2(float lo, float hi) {  // packed: lo->low16, hi->high16
    float2 t; t.x = lo; t.y = hi;
    __hip_bfloat162 h = __float22bfloat162_rn(t);
    union { __hip_bfloat162 b; uint u; } cv;
    cv.b = h;
    return cv.u;
}

// prep: geoms f32 -> bf16 table in d_ws
__global__ void prep_geoms(const float* __restrict__ g, ushort* __restrict__ gb, int n) {
    int i = blockIdx.x * 256 + threadIdx.x;
    if (i < n) gb[i] = f2bf(g[i]);
}

// f64 adjugate 4x4 inverse; writes rows 0..2 (3x4 floats) to ti
__device__ inline void inv4x4(float4 t0, float4 t1, float4 t2, float4 t3,
                              float* __restrict__ ti) {
    double m00=t0.x, m01=t0.y, m02=t0.z, m03=t0.w;
    double m10=t1.x, m11=t1.y, m12=t1.z, m13=t1.w;
    double m20=t2.x, m21=t2.y, m22=t2.z, m23=t2.w;
    double m30=t3.x, m31=t3.y, m32=t3.z, m33=t3.w;
    double A2323 = m22*m33 - m23*m32;
    double A1323 = m21*m33 - m23*m31;
    double A1223 = m21*m32 - m22*m31;
    double A0323 = m20*m33 - m23*m30;
    double A0223 = m20*m32 - m22*m30;
    double A0123 = m20*m31 - m21*m30;
    double A2313 = m12*m33 - m13*m32;
    double A1313 = m11*m33 - m13*m31;
    double A1213 = m11*m32 - m12*m31;
    double A2312 = m12*m23 - m13*m22;
    double A1312 = m11*m23 - m13*m21;
    double A1212 = m11*m22 - m12*m21;
    double A0313 = m10*m33 - m13*m30;
    double A0213 = m10*m32 - m12*m30;
    double A0312 = m10*m23 - m13*m20;
    double A0212 = m10*m22 - m12*m20;
    double A0113 = m10*m31 - m11*m30;
    double A0112 = m10*m21 - m11*m20;
    double det = m00*(m11*A2323 - m12*A1323 + m13*A1223)
               - m01*(m10*A2323 - m12*A0323 + m13*A0223)
               + m02*(m10*A1323 - m11*A0323 + m13*A0123)
               - m03*(m10*A1223 - m11*A0223 + m12*A0123);
    double idet = 1.0 / det;
    ti[0]  = (float)( idet *  (m11*A2323 - m12*A1323 + m13*A1223) );
    ti[1]  = (float)( idet * -(m01*A2323 - m02*A1323 + m03*A1223) );
    ti[2]  = (float)( idet *  (m01*A2313 - m02*A1313 + m03*A1213) );
    ti[3]  = (float)( idet * -(m01*A2312 - m02*A1312 + m03*A1212) );
    ti[4]  = (float)( idet * -(m10*A2323 - m12*A0323 + m13*A0223) );
    ti[5]  = (float)( idet *  (m00*A2323 - m02*A0323 + m03*A0223) );
    ti[6]  = (float)( idet * -(m00*A2313 - m02*A0313 + m03*A0213) );
    ti[7]  = (float)( idet *  (m00*A2312 - m02*A0312 + m03*A0212) );
    ti[8]  = (float)( idet *  (m10*A1323 - m11*A0323 + m13*A0123) );
    ti[9]  = (float)( idet * -(m00*A1323 - m01*A0323 + m03*A0123) );
    ti[10] = (float)( idet *  (m00*A1313 - m01*A0313 + m03*A0113) );
    ti[11] = (float)( idet * -(m00*A1312 - m01*A0312 + m03*A0112) );
}

__global__ void __launch_bounds__(BT, 4) collision_mfma(
    const int* __restrict__ o1, const int* __restrict__ o2,
    const float* __restrict__ Tg, const float* __restrict__ geoms,
    const ushort* __restrict__ gbf,
    const float* __restrict__ W1, const float* __restrict__ b1,
    const float* __restrict__ W2, const float* __restrict__ b2,
    const float* __restrict__ W3, const float* __restrict__ b3,
    float* __restrict__ out, int N)
{
    __shared__ ushort xs[512 * LDX];    // x/h tile bf16, wave-private 32-row bands (106496 B)
    __shared__ ushort w1t[KD * LDX];    // W1^T bf16 [n][k] (19968 B)
    __shared__ ushort w2t[KD * LDX];    // W2^T bf16 [n][k] (19968 B)
    __shared__ float  tinv[256 * LDT];  // per-pair inverse rows 0..2 (12288 B)

    const int tid = threadIdx.x;
    const int w   = tid >> 6;      // wave 0..15
    const int l   = tid & 63;      // lane
    const int cl  = l & 15;        // fragment col within 16-tile
    const int g   = l >> 4;        // k-group 0..3
    const int rg  = g * 4;

    // staging roles (fixed per lane)
    const int rl = l & 31;         // local row 0..31
    const int pt = l >> 5;         // part: elems [pt*24, pt*24+24)
    const int br = rl >> 4;        // branch 0: (x1, T x2)  1: (x2, Tinv x1)
    const int dp = rl & 15;        // local pair 0..15

    // ---- stage weights once: wt[n][k] = W[k][n], bf16 ----
    for (int i = tid; i < KD * KD; i += BT) {
        int k = i / KD;
        int n = i - k * KD;
        w1t[n * LDX + k] = f2bf(W1[i]);
        w2t[n * LDX + k] = f2bf(W2[i]);
    }
    __syncthreads();   // only runtime barrier; main loop is wave-private

    const int NWT = N >> 4;                    // 62500 wave-tiles of 16 pairs
    const int gw  = blockIdx.x * (BT / 64) + w;

    for (int wt = gw; wt < NWT; wt += TOTW) {
        const int pbase = wt * 16;

        // ===== phase 1: f64 4x4 inverse, lanes 0..15, one pair each =====
        if (l < 16) {
            const float4* T4 = reinterpret_cast<const float4*>(Tg + (size_t)(pbase + l) * 16);
            float4 t0 = T4[0], t1 = T4[1], t2 = T4[2], t3 = T4[3];
            inv4x4(t0, t1, t2, t3, &tinv[(w * 16 + l) * LDT]);
        }
        asm volatile("" ::: "memory");   // fence (in-wave DS order gives correctness)

        // ===== phase 2: staging, lane = half-row =====
        {
            const int p  = pbase + dp;
            const int ia = o1[p], ib = o2[p];
            const int oa = br ? ib : ia;
            const int ob = br ? ia : ib;
            ushort* xrow = xs + (w * 32 + rl) * LDX;

            // copy half (24 bf16 from pre-converted table)
            {
                const uint4* src = reinterpret_cast<const uint4*>(gbf + oa * 48 + pt * 24);
                uint4* dst = reinterpret_cast<uint4*>(xrow + pt * 24);
                dst[0] = src[0]; dst[1] = src[1]; dst[2] = src[2];
            }

            // transform half: 8 vec3s
            float4 M0, M1, M2;
            if (br == 0) {
                const float4* Tp = reinterpret_cast<const float4*>(Tg + (size_t)p * 16);
                M0 = Tp[0]; M1 = Tp[1]; M2 = Tp[2];
            } else {
                const float* ti = &tinv[(w * 16 + dp) * LDT];
                const float4* t4 = reinterpret_cast<const float4*>(ti);
                M0 = t4[0]; M1 = t4[1]; M2 = t4[2];
            }
            float v[24];
            {
                const float4* bs = reinterpret_cast<const float4*>(geoms + (size_t)ob * 48 + pt * 24);
                #pragma unroll
                for (int q = 0; q < 6; ++q) {
                    float4 t = bs[q];
                    v[4*q+0] = t.x; v[4*q+1] = t.y; v[4*q+2] = t.z; v[4*q+3] = t.w;
                }
            }
            float o[24];
            #pragma unroll
            for (int m = 0; m < 8; ++m) {
                float vx = v[3*m+0], vy = v[3*m+1], vz = v[3*m+2];
                o[3*m+0] = fmaf(M0.x, vx, fmaf(M0.y, vy, fmaf(M0.z, vz, M0.w)));
                o[3*m+1] = fmaf(M1.x, vx, fmaf(M1.y, vy, fmaf(M1.z, vz, M1.w)));
                o[3*m+2] = fmaf(M2.x, vx, fmaf(M2.y, vy, fmaf(M2.z, vz, M2.w)));
            }
            union { uint u[12]; uint4 q4[3]; } pk;
            #pragma unroll
            for (int q = 0; q < 12; ++q)
                pk.u[q] = f2bf2(o[2*q], o[2*q+1]);
            uint4* dst = reinterpret_cast<uint4*>(xrow + 48 + pt * 24);
            dst[0] = pk.q4[0]; dst[1] = pk.q4[1]; dst[2] = pk.q4[2];
        }
        asm volatile("" ::: "memory");   // fence: stop LICM of weight ds_reads

        // ===== layer 1: acc[mt][nt] = W1^T-frag x x-frag =====
        f32x4 acc[6][2];
        #pragma unroll
        for (int mt = 0; mt < 6; ++mt) {
            acc[mt][0] = (f32x4){0.f, 0.f, 0.f, 0.f};
            acc[mt][1] = (f32x4){0.f, 0.f, 0.f, 0.f};
        }
        bf16x8 xf[2][3];
        #pragma unroll
        for (int nt = 0; nt < 2; ++nt)
            #pragma unroll
            for (int kb = 0; kb < 3; ++kb)
                xf[nt][kb] = *reinterpret_cast<const bf16x8*>(
                    xs + (w*32 + nt*16 + cl) * LDX + kb*32 + g*8);
        #pragma unroll
        for (int mt = 0; mt < 6; ++mt) {
            bf16x8 wfr[3];
            #pragma unroll
            for (int kb = 0; kb < 3; ++kb)
                wfr[kb] = *reinterpret_cast<const bf16x8*>(
                    w1t + (mt*16 + cl) * LDX + kb*32 + g*8);
            #pragma unroll
            for (int nt = 0; nt < 2; ++nt)
                #pragma unroll
                for (int kb = 0; kb < 3; ++kb)
                    acc[mt][nt] = __builtin_amdgcn_mfma_f32_16x16x32_bf16(
                        wfr[kb], xf[nt][kb], acc[mt][nt], 0, 0, 0);
        }

        // epilogue 1: +bias, relu -> packed bf16, b64 write
        #pragma unroll
        for (int mt = 0; mt < 6; ++mt) {
            float4 bv = *reinterpret_cast<const float4*>(b1 + mt*16 + rg);
            #pragma unroll
            for (int nt = 0; nt < 2; ++nt) {
                uint2 u2;
                u2.x = f2bf2(fmaxf(acc[mt][nt][0] + bv.x, 0.f),
                             fmaxf(acc[mt][nt][1] + bv.y, 0.f));
                u2.y = f2bf2(fmaxf(acc[mt][nt][2] + bv.z, 0.f),
                             fmaxf(acc[mt][nt][3] + bv.w, 0.f));
                *reinterpret_cast<uint2*>(
                    xs + (w*32 + nt*16 + cl) * LDX + mt*16 + rg) = u2;
            }
        }
        asm volatile("" ::: "memory");   // fence between layers

        // ===== layer 2 =====
        f32x4 acc2[6][2];
        #pragma unroll
        for (int mt = 0; mt < 6; ++mt) {
            acc2[mt][0] = (f32x4){0.f, 0.f, 0.f, 0.f};
            acc2[mt][1] = (f32x4){0.f, 0.f, 0.f, 0.f};
        }
        bf16x8 hf[2][3];
        #pragma unroll
        for (int nt = 0; nt < 2; ++nt)
            #pragma unroll
            for (int kb = 0; kb < 3; ++kb)
                hf[nt][kb] = *reinterpret_cast<const bf16x8*>(
                    xs + (w*32 + nt*16 + cl) * LDX + kb*32 + g*8);
        #pragma unroll
        for (int mt = 0; mt < 6; ++mt) {
            bf16x8 wfr[3];
            #pragma unroll
            for (int kb = 0; kb < 3; ++kb)
                wfr[kb] = *reinterpret_cast<const bf16x8*>(
                    w2t + (mt*16 + cl) * LDX + kb*32 + g*8);
            #pragma unroll
            for (int nt = 0; nt < 2; ++nt)
                #pragma unroll
                for (int kb = 0; kb < 3; ++kb)
                    acc2[mt][nt] = __builtin_amdgcn_mfma_f32_16x16x32_bf16(
                        wfr[kb], hf[nt][kb], acc2[mt][nt], 0, 0, 0);
        }

        // epilogue 2: +bias, relu, W3 dot, 2 shuffles, coalesced store
        float pr0 = 0.f, pr1 = 0.f;
        #pragma unroll
        for (int mt = 0; mt < 6; ++mt) {
            float4 bv  = *reinterpret_cast<const float4*>(b2 + mt*16 + rg);
            float4 w3v = *reinterpret_cast<const float4*>(W3 + mt*16 + rg);
            pr0 = fmaf(fmaxf(acc2[mt][0][0] + bv.x, 0.f), w3v.x, pr0);
            pr0 = fmaf(fmaxf(acc2[mt][0][1] + bv.y, 0.f), w3v.y, pr0);
            pr0 = fmaf(fmaxf(acc2[mt][0][2] + bv.z, 0.f), w3v.z, pr0);
            pr0 = fmaf(fmaxf(acc2[mt][0][3] + bv.w, 0.f), w3v.w, pr0);
            pr1 = fmaf(fmaxf(acc2[mt][1][0] + bv.x, 0.f), w3v.x, pr1);
            pr1 = fmaf(fmaxf(acc2[mt][1][1] + bv.y, 0.f), w3v.y, pr1);
            pr1 = fmaf(fmaxf(acc2[mt][1][2] + bv.z, 0.f), w3v.z, pr1);
            pr1 = fmaf(fmaxf(acc2[mt][1][3] + bv.w, 0.f), w3v.w, pr1);
        }
        pr0 += __shfl_xor(pr0, 16, 64);
        pr0 += __shfl_xor(pr0, 32, 64);
        pr1 += __shfl_xor(pr1, 16, 64);
        pr1 += __shfl_xor(pr1, 32, 64);
        if (l < 16)
            out[pbase + l] = 0.5f * (pr0 + pr1) + b3[0];

        asm volatile("" ::: "memory");   // fence at loop end
    }
}

extern "C" void kernel_launch(void* const* d_in, const int* in_sizes, int n_in,
                              void* d_out, int out_size, void* d_ws, size_t ws_size,
                              hipStream_t stream) {
    const int*   o1    = (const int*)d_in[0];
    const int*   o2    = (const int*)d_in[1];
    const float* T     = (const float*)d_in[2];
    const float* geoms = (const float*)d_in[3];
    const float* W1    = (const float*)d_in[4];
    const float* b1    = (const float*)d_in[5];
    const float* W2    = (const float*)d_in[6];
    const float* b2    = (const float*)d_in[7];
    const float* W3    = (const float*)d_in[8];
    const float* b3    = (const float*)d_in[9];
    float* out = (float*)d_out;
    const int N  = in_sizes[0];
    const int NG = in_sizes[3];           // 48000

    ushort* gbf = (ushort*)d_ws;
    hipLaunchKernelGGL(prep_geoms, dim3((NG + 255) / 256), dim3(256), 0, stream,
                       geoms, gbf, NG);
    hipLaunchKernelGGL(collision_mfma, dim3(NBLK), dim3(BT), 0, stream,
                       o1, o2, T, geoms, gbf, W1, b1, W2, b2, W3, b3, out, N);
}

// Round 10
// 133.025 us; speedup vs baseline: 1.5447x; 1.0285x over previous
//
#include <hip/hip_runtime.h>
#include <hip/hip_bf16.h>

typedef __attribute__((ext_vector_type(8))) short bf16x8;
typedef __attribute__((ext_vector_type(4))) float f32x4;

constexpr int BT   = 1024;  // threads/block (16 waves, 1 block/CU)
constexpr int KD   = 96;    // feature/hidden dim
constexpr int LDX  = 104;   // LDS row stride in bf16 (208 B, 16B-aligned)
constexpr int LDT  = 12;    // tinv stride in floats (48 B, 16B-aligned)
constexpr int NBLK = 256;   // persistent blocks (1 per CU)
constexpr int TOTW = NBLK * (BT / 64);   // 4096 waves in flight

__device__ inline ushort f2bf(float f) {  // fp32 -> bf16 RNE (prep/weights only)
    uint u = __float_as_uint(f);
    u += 0x7fffu + ((u >> 16) & 1u);
    return (ushort)(u >> 16);
}

__device__ inline uint f2bf2(float lo, float hi) {  // packed: lo->low16, hi->high16
    float2 t; t.x = lo; t.y = hi;
    __hip_bfloat162 h = __float22bfloat162_rn(t);
    union { __hip_bfloat162 b; uint u; } cv;
    cv.b = h;
    return cv.u;
}

// prep: geoms f32 -> bf16 table in d_ws
__global__ void prep_geoms(const float* __restrict__ g, ushort* __restrict__ gb, int n) {
    int i = blockIdx.x * 256 + threadIdx.x;
    if (i < n) gb[i] = f2bf(g[i]);
}

// f64 adjugate 4x4 inverse; writes rows 0..2 (3x4 floats) to ti
__device__ inline void inv4x4(float4 t0, float4 t1, float4 t2, float4 t3,
                              float* __restrict__ ti) {
    double m00=t0.x, m01=t0.y, m02=t0.z, m03=t0.w;
    double m10=t1.x, m11=t1.y, m12=t1.z, m13=t1.w;
    double m20=t2.x, m21=t2.y, m22=t2.z, m23=t2.w;
    double m30=t3.x, m31=t3.y, m32=t3.z, m33=t3.w;
    double A2323 = m22*m33 - m23*m32;
    double A1323 = m21*m33 - m23*m31;
    double A1223 = m21*m32 - m22*m31;
    double A0323 = m20*m33 - m23*m30;
    double A0223 = m20*m32 - m22*m30;
    double A0123 = m20*m31 - m21*m30;
    double A2313 = m12*m33 - m13*m32;
    double A1313 = m11*m33 - m13*m31;
    double A1213 = m11*m32 - m12*m31;
    double A2312 = m12*m23 - m13*m22;
    double A1312 = m11*m23 - m13*m21;
    double A1212 = m11*m22 - m12*m21;
    double A0313 = m10*m33 - m13*m30;
    double A0213 = m10*m32 - m12*m30;
    double A0312 = m10*m23 - m13*m20;
    double A0212 = m10*m22 - m12*m20;
    double A0113 = m10*m31 - m11*m30;
    double A0112 = m10*m21 - m11*m20;
    double det = m00*(m11*A2323 - m12*A1323 + m13*A1223)
               - m01*(m10*A2323 - m12*A0323 + m13*A0223)
               + m02*(m10*A1323 - m11*A0323 + m13*A0123)
               - m03*(m10*A1223 - m11*A0223 + m12*A0123);
    double idet = 1.0 / det;
    ti[0]  = (float)( idet *  (m11*A2323 - m12*A1323 + m13*A1223) );
    ti[1]  = (float)( idet * -(m01*A2323 - m02*A1323 + m03*A1223) );
    ti[2]  = (float)( idet *  (m01*A2313 - m02*A1313 + m03*A1213) );
    ti[3]  = (float)( idet * -(m01*A2312 - m02*A1312 + m03*A1212) );
    ti[4]  = (float)( idet * -(m10*A2323 - m12*A0323 + m13*A0223) );
    ti[5]  = (float)( idet *  (m00*A2323 - m02*A0323 + m03*A0223) );
    ti[6]  = (float)( idet * -(m00*A2313 - m02*A0313 + m03*A0213) );
    ti[7]  = (float)( idet *  (m00*A2312 - m02*A0312 + m03*A0212) );
    ti[8]  = (float)( idet *  (m10*A1323 - m11*A0323 + m13*A0123) );
    ti[9]  = (float)( idet * -(m00*A1323 - m01*A0323 + m03*A0123) );
    ti[10] = (float)( idet *  (m00*A1313 - m01*A0313 + m03*A0113) );
    ti[11] = (float)( idet * -(m00*A1312 - m01*A0312 + m03*A0112) );
}

__global__ void __launch_bounds__(BT, 4) collision_mfma(
    const int* __restrict__ o1, const int* __restrict__ o2,
    const float* __restrict__ Tg, const float* __restrict__ geoms,
    const ushort* __restrict__ gbf,
    const float* __restrict__ W1, const float* __restrict__ b1,
    const float* __restrict__ W2, const float* __restrict__ b2,
    const float* __restrict__ W3, const float* __restrict__ b3,
    float* __restrict__ out, int N)
{
    __shared__ ushort xs[512 * LDX];    // x/h tile bf16, wave-private 32-row bands (106496 B)
    __shared__ ushort w1t[KD * LDX];    // W1^T bf16 [n][k] (19968 B)
    __shared__ ushort w2t[KD * LDX];    // W2^T bf16 [n][k] (19968 B)
    __shared__ float  tinv[256 * LDT];  // per-pair inverse rows 0..2 (12288 B)
    __shared__ float  bls[292];         // b1[0..96) | b2[96..192) | W3[192..288) | b3[288]

    const int tid = threadIdx.x;
    const int w   = tid >> 6;      // wave 0..15
    const int l   = tid & 63;      // lane
    const int cl  = l & 15;        // fragment col within 16-tile
    const int g   = l >> 4;        // k-group 0..3
    const int rg  = g * 4;

    // staging roles (fixed per lane)
    const int rl = l & 31;         // local row 0..31
    const int pt = l >> 5;         // part: elems [pt*24, pt*24+24)
    const int br = rl >> 4;        // branch 0: (x1, T x2)  1: (x2, Tinv x1)
    const int dp = rl & 15;        // local pair 0..15

    // ---- stage weights + bias/W3 once ----
    for (int i = tid; i < KD * KD; i += BT) {
        int k = i / KD;
        int n = i - k * KD;
        w1t[n * LDX + k] = f2bf(W1[i]);
        w2t[n * LDX + k] = f2bf(W2[i]);
    }
    if (tid < 96) {
        bls[tid]       = b1[tid];
        bls[96 + tid]  = b2[tid];
        bls[192 + tid] = W3[tid];
    }
    if (tid == 96) bls[288] = b3[0];
    __syncthreads();   // only runtime barrier; main loop is wave-private

    const int NWT = N >> 4;                    // 62500 wave-tiles of 16 pairs
    const int gw  = blockIdx.x * (BT / 64) + w;

    for (int wt = gw; wt < NWT; wt += TOTW) {
        const int pbase = wt * 16;

        // ===== phase 1: f64 4x4 inverse, lanes 0..15, one pair each =====
        if (l < 16) {
            const float4* T4 = reinterpret_cast<const float4*>(Tg + (size_t)(pbase + l) * 16);
            float4 t0 = T4[0], t1 = T4[1], t2 = T4[2], t3 = T4[3];
            inv4x4(t0, t1, t2, t3, &tinv[(w * 16 + l) * LDT]);
        }
        asm volatile("" ::: "memory");   // fence (in-wave DS order gives correctness)

        // ===== phase 2: staging, lane = half-row =====
        {
            const int p  = pbase + dp;
            const int ia = o1[p], ib = o2[p];
            const int oa = br ? ib : ia;
            const int ob = br ? ia : ib;
            ushort* xrow = xs + (w * 32 + rl) * LDX;

            // copy half (24 bf16 from pre-converted table)
            {
                const uint4* src = reinterpret_cast<const uint4*>(gbf + oa * 48 + pt * 24);
                uint4* dst = reinterpret_cast<uint4*>(xrow + pt * 24);
                dst[0] = src[0]; dst[1] = src[1]; dst[2] = src[2];
            }

            // transform half: 8 vec3s
            float4 M0, M1, M2;
            if (br == 0) {
                const float4* Tp = reinterpret_cast<const float4*>(Tg + (size_t)p * 16);
                M0 = Tp[0]; M1 = Tp[1]; M2 = Tp[2];
            } else {
                const float4* t4 = reinterpret_cast<const float4*>(&tinv[(w * 16 + dp) * LDT]);
                M0 = t4[0]; M1 = t4[1]; M2 = t4[2];
            }
            float v[24];
            {
                const float4* bs = reinterpret_cast<const float4*>(geoms + (size_t)ob * 48 + pt * 24);
                #pragma unroll
                for (int q = 0; q < 6; ++q) {
                    float4 t = bs[q];
                    v[4*q+0] = t.x; v[4*q+1] = t.y; v[4*q+2] = t.z; v[4*q+3] = t.w;
                }
            }
            float o[24];
            #pragma unroll
            for (int m = 0; m < 8; ++m) {
                float vx = v[3*m+0], vy = v[3*m+1], vz = v[3*m+2];
                o[3*m+0] = fmaf(M0.x, vx, fmaf(M0.y, vy, fmaf(M0.z, vz, M0.w)));
                o[3*m+1] = fmaf(M1.x, vx, fmaf(M1.y, vy, fmaf(M1.z, vz, M1.w)));
                o[3*m+2] = fmaf(M2.x, vx, fmaf(M2.y, vy, fmaf(M2.z, vz, M2.w)));
            }
            union { uint u[12]; uint4 q4[3]; } pk;
            #pragma unroll
            for (int q = 0; q < 12; ++q)
                pk.u[q] = f2bf2(o[2*q], o[2*q+1]);
            uint4* dst = reinterpret_cast<uint4*>(xrow + 48 + pt * 24);
            dst[0] = pk.q4[0]; dst[1] = pk.q4[1]; dst[2] = pk.q4[2];
        }
        asm volatile("" ::: "memory");   // fence: stop LICM of weight/bias ds_reads

        // ===== layer 1: acc init = b1 (from LDS), then W1^T-frag x x-frag =====
        f32x4 acc[6][2];
        #pragma unroll
        for (int mt = 0; mt < 6; ++mt) {
            f32x4 bv = *reinterpret_cast<const f32x4*>(&bls[mt*16 + rg]);
            acc[mt][0] = bv;
            acc[mt][1] = bv;
        }
        bf16x8 xf[2][3];
        #pragma unroll
        for (int nt = 0; nt < 2; ++nt)
            #pragma unroll
            for (int kb = 0; kb < 3; ++kb)
                xf[nt][kb] = *reinterpret_cast<const bf16x8*>(
                    xs + (w*32 + nt*16 + cl) * LDX + kb*32 + g*8);
        #pragma unroll
        for (int mt = 0; mt < 6; ++mt) {
            bf16x8 wfr[3];
            #pragma unroll
            for (int kb = 0; kb < 3; ++kb)
                wfr[kb] = *reinterpret_cast<const bf16x8*>(
                    w1t + (mt*16 + cl) * LDX + kb*32 + g*8);
            #pragma unroll
            for (int nt = 0; nt < 2; ++nt)
                #pragma unroll
                for (int kb = 0; kb < 3; ++kb)
                    acc[mt][nt] = __builtin_amdgcn_mfma_f32_16x16x32_bf16(
                        wfr[kb], xf[nt][kb], acc[mt][nt], 0, 0, 0);
        }

        // epilogue 1: relu -> packed bf16, b64 write (bias already in acc)
        #pragma unroll
        for (int mt = 0; mt < 6; ++mt) {
            #pragma unroll
            for (int nt = 0; nt < 2; ++nt) {
                uint2 u2;
                u2.x = f2bf2(fmaxf(acc[mt][nt][0], 0.f), fmaxf(acc[mt][nt][1], 0.f));
                u2.y = f2bf2(fmaxf(acc[mt][nt][2], 0.f), fmaxf(acc[mt][nt][3], 0.f));
                *reinterpret_cast<uint2*>(
                    xs + (w*32 + nt*16 + cl) * LDX + mt*16 + rg) = u2;
            }
        }
        asm volatile("" ::: "memory");   // fence between layers

        // ===== layer 2: acc2 init = b2 (from LDS) =====
        f32x4 acc2[6][2];
        #pragma unroll
        for (int mt = 0; mt < 6; ++mt) {
            f32x4 bv = *reinterpret_cast<const f32x4*>(&bls[96 + mt*16 + rg]);
            acc2[mt][0] = bv;
            acc2[mt][1] = bv;
        }
        bf16x8 hf[2][3];
        #pragma unroll
        for (int nt = 0; nt < 2; ++nt)
            #pragma unroll
            for (int kb = 0; kb < 3; ++kb)
                hf[nt][kb] = *reinterpret_cast<const bf16x8*>(
                    xs + (w*32 + nt*16 + cl) * LDX + kb*32 + g*8);
        #pragma unroll
        for (int mt = 0; mt < 6; ++mt) {
            bf16x8 wfr[3];
            #pragma unroll
            for (int kb = 0; kb < 3; ++kb)
                wfr[kb] = *reinterpret_cast<const bf16x8*>(
                    w2t + (mt*16 + cl) * LDX + kb*32 + g*8);
            #pragma unroll
            for (int nt = 0; nt < 2; ++nt)
                #pragma unroll
                for (int kb = 0; kb < 3; ++kb)
                    acc2[mt][nt] = __builtin_amdgcn_mfma_f32_16x16x32_bf16(
                        wfr[kb], hf[nt][kb], acc2[mt][nt], 0, 0, 0);
        }

        // epilogue 2: relu + W3 dot (W3 from LDS), 2 shuffles, coalesced store
        float pr0 = 0.f, pr1 = 0.f;
        #pragma unroll
        for (int mt = 0; mt < 6; ++mt) {
            f32x4 w3v = *reinterpret_cast<const f32x4*>(&bls[192 + mt*16 + rg]);
            pr0 = fmaf(fmaxf(acc2[mt][0][0], 0.f), w3v[0], pr0);
            pr0 = fmaf(fmaxf(acc2[mt][0][1], 0.f), w3v[1], pr0);
            pr0 = fmaf(fmaxf(acc2[mt][0][2], 0.f), w3v[2], pr0);
            pr0 = fmaf(fmaxf(acc2[mt][0][3], 0.f), w3v[3], pr0);
            pr1 = fmaf(fmaxf(acc2[mt][1][0], 0.f), w3v[0], pr1);
            pr1 = fmaf(fmaxf(acc2[mt][1][1], 0.f), w3v[1], pr1);
            pr1 = fmaf(fmaxf(acc2[mt][1][2], 0.f), w3v[2], pr1);
            pr1 = fmaf(fmaxf(acc2[mt][1][3], 0.f), w3v[3], pr1);
        }
        pr0 += __shfl_xor(pr0, 16, 64);
        pr0 += __shfl_xor(pr0, 32, 64);
        pr1 += __shfl_xor(pr1, 16, 64);
        pr1 += __shfl_xor(pr1, 32, 64);
        if (l < 16)
            out[pbase + l] = 0.5f * (pr0 + pr1) + bls[288];

        asm volatile("" ::: "memory");   // fence at loop end
    }
}

extern "C" void kernel_launch(void* const* d_in, const int* in_sizes, int n_in,
                              void* d_out, int out_size, void* d_ws, size_t ws_size,
                              hipStream_t stream) {
    const int*   o1    = (const int*)d_in[0];
    const int*   o2    = (const int*)d_in[1];
    const float* T     = (const float*)d_in[2];
    const float* geoms = (const float*)d_in[3];
    const float* W1    = (const float*)d_in[4];
    const float* b1    = (const float*)d_in[5];
    const float* W2    = (const float*)d_in[6];
    const float* b2    = (const float*)d_in[7];
    const float* W3    = (const float*)d_in[8];
    const float* b3    = (const float*)d_in[9];
    float* out = (float*)d_out;
    const int N  = in_sizes[0];
    const int NG = in_sizes[3];           // 48000

    ushort* gbf = (ushort*)d_ws;
    hipLaunchKernelGGL(prep_geoms, dim3((NG + 255) / 256), dim3(256), 0, stream,
                       geoms, gbf, NG);
    hipLaunchKernelGGL(collision_mfma, dim3(NBLK), dim3(BT), 0, stream,
                       o1, o2, T, geoms, gbf, W1, b1, W2, b2, W3, b3, out, N);
}